// Round 13
// baseline (382.352 us; speedup 1.0000x reference)
//
#include <hip/hip_runtime.h>
#include <hip/hip_bf16.h>
#include <math.h>

#define N_NODES 20000
#define N_EDGES 320000
#define DIM 512
#define HEADS 4
#define DHEAD 128
#define NEG_SLOPE 0.2f
#define BM 64
#define BN 64
#define BK 64
#define GEMM_BLOCKS 2504   // 313 * 8
#define ALS_BLOCKS 5000    // 4 nodes per block

typedef __attribute__((ext_vector_type(8))) short short8;
typedef __attribute__((ext_vector_type(8))) __bf16 bf16x8;
typedef __attribute__((ext_vector_type(4))) float f32x4;

static __device__ __forceinline__ unsigned short f32_to_bf16(float f) {
    union { float f; unsigned u; } v; v.f = f;
    unsigned u = v.u;
    u += 0x7FFFu + ((u >> 16) & 1u);   // round-to-nearest-even
    return (unsigned short)(u >> 16);
}
static __device__ __forceinline__ float bf16_to_f32(unsigned short s) {
    union { unsigned u; float f; } v; v.u = ((unsigned)s) << 16;
    return v.f;
}

static __device__ __forceinline__ void gl_lds16(const unsigned short* g, unsigned short* l) {
    __builtin_amdgcn_global_load_lds(
        (const __attribute__((address_space(1))) unsigned int*)g,
        (__attribute__((address_space(3))) unsigned int*)l, 16, 0, 0);
}

// ---------------- fused prologue: cast | transW x2 | wtilde x2 | hist ----------------
static __device__ __forceinline__ void do_cast(const float* in, unsigned short* out, int i) {
    const float4* p = reinterpret_cast<const float4*>(in) + (size_t)i * 2;
    float4 a = p[0], b = p[1];
    short8 o;
    o[0] = (short)f32_to_bf16(a.x); o[1] = (short)f32_to_bf16(a.y);
    o[2] = (short)f32_to_bf16(a.z); o[3] = (short)f32_to_bf16(a.w);
    o[4] = (short)f32_to_bf16(b.x); o[5] = (short)f32_to_bf16(b.y);
    o[6] = (short)f32_to_bf16(b.z); o[7] = (short)f32_to_bf16(b.w);
    *reinterpret_cast<short8*>(out + (size_t)i * 8) = o;
}
static __device__ __forceinline__ void do_transW(const float* W, unsigned short* Bt, int id) {
    int col = id >> 6;
    int kg = id & 63;
    int h = col >> 7;
    int f = col & 127;
    short8 o;
#pragma unroll
    for (int j = 0; j < 8; j++) {
        int k = kg * 8 + j;
        o[j] = (short)f32_to_bf16(W[(size_t)h * DIM * DHEAD + (size_t)k * DHEAD + f]);
    }
    *reinterpret_cast<short8*>(Bt + (size_t)col * DIM + kg * 8) = o;
}
static __device__ __forceinline__ void do_wtilde(const float* W, const float* a, float* wt, int id) {
    int v = id >> 9, k = id & 511;
    int h = v >> 1, sd = v & 1;
    const float* Wr = W + ((size_t)h * DIM + k) * DHEAD;
    const float* av = a + h * 2 * DHEAD + sd * DHEAD;
    float s = 0.f;
#pragma unroll 4
    for (int f = 0; f < DHEAD; f++) s += Wr[f] * av[f];
    wt[(size_t)v * DIM + k] = s;
}

__global__ void k_prep(const float* __restrict__ x, unsigned short* __restrict__ xb,
                       const float* __restrict__ W1, unsigned short* __restrict__ B1,
                       const float* __restrict__ W2, unsigned short* __restrict__ B2,
                       const float* __restrict__ a1, float* __restrict__ wt1,
                       const float* __restrict__ a2, float* __restrict__ wt2,
                       const int* __restrict__ dst, int* __restrict__ counts) {
    int b = blockIdx.x, tid = threadIdx.x;
    if (b < 5000) {
        do_cast(x, xb, b * 256 + tid);
    } else if (b < 5128) {
        do_transW(W1, B1, (b - 5000) * 256 + tid);
    } else if (b < 5256) {
        do_transW(W2, B2, (b - 5128) * 256 + tid);
    } else if (b < 5272) {
        do_wtilde(W1, a1, wt1, (b - 5256) * 256 + tid);
    } else if (b < 5288) {
        do_wtilde(W2, a2, wt2, (b - 5272) * 256 + tid);
    } else {
        int e = (b - 5288) * 256 + tid;
        if (e < N_EDGES) atomicAdd(&counts[dst[e]], 1);
    }
}

// ---------------- CSR build ----------------
__global__ void k_scan(const int* __restrict__ counts, int* __restrict__ offsets,
                       int* __restrict__ cursor) {
    __shared__ int lds[1024];
    int t = threadIdx.x;
    const int CH = (N_NODES + 1023) / 1024;   // 20
    int base = t * CH;
    int sum = 0;
    for (int j = 0; j < CH; j++) {
        int i = base + j;
        if (i < N_NODES) sum += counts[i];
    }
    lds[t] = sum;
    __syncthreads();
    for (int off = 1; off < 1024; off <<= 1) {
        int other = (t >= off) ? lds[t - off] : 0;
        __syncthreads();
        lds[t] += other;
        __syncthreads();
    }
    int excl = lds[t] - sum;
    int run = excl;
    for (int j = 0; j < CH; j++) {
        int i = base + j;
        if (i < N_NODES) {
            offsets[i] = run;
            cursor[i] = run;
            run += counts[i];
        }
    }
    if (t == 0) offsets[N_NODES] = N_EDGES;
}

__global__ void k_fill(const int* __restrict__ src, const int* __restrict__ dst,
                       int* __restrict__ cursor, int* __restrict__ csr_src) {
    int e = blockIdx.x * blockDim.x + threadIdx.x;
    if (e >= N_EDGES) return;
    int d = dst[e];
    int p = atomicAdd(&cursor[d], 1);
    csr_src[p] = src[e];
}

// ---------------- fused GEMM + attention logits (independent roles, shared 16KB LDS) ----------
#define MFMA(a, b, c) __builtin_amdgcn_mfma_f32_16x16x32_bf16(a, b, c, 0, 0, 0)

__global__ __launch_bounds__(256, 8) void k_gemm_als(const unsigned short* __restrict__ A,
                                                     const unsigned short* __restrict__ Bt,
                                                     unsigned short* __restrict__ Hout,
                                                     const float* __restrict__ wt,
                                                     float* __restrict__ als,
                                                     float* __restrict__ ald) {
    __shared__ __align__(16) char sbuf[16384];
    const int tid = threadIdx.x;

    if (blockIdx.x < GEMM_BLOCKS) {
        unsigned short* lds = (unsigned short*)sbuf;
        // bijective XCD swizzle: 2504 = 8 * 313 exactly
        const int orig = blockIdx.x;
        const int wgid = (orig & 7) * 313 + (orig >> 3);
        const int mb = wgid >> 3, nb = wgid & 7;
        const int m0 = mb * BM, n0 = nb * BN;
        const int lane = tid & 63, wid = tid >> 6;
        const int wm = wid >> 1, wn = wid & 1;
        const int lr = lane & 15, kq = lane >> 4;

        f32x4 acc[2][2];
#pragma unroll
        for (int i = 0; i < 2; i++)
#pragma unroll
            for (int j = 0; j < 2; j++) acc[i][j] = (f32x4){0.f, 0.f, 0.f, 0.f};

#pragma unroll 1
        for (int t = 0; t < 8; t++) {
            const int k0 = t * BK;
#pragma unroll
            for (int it = 0; it < 4; it++) {
                const int region = it >> 1;              // 0=A 1=B
                int c = (it & 1) * 256 + tid;            // 0..511
                int row = c >> 3;                        // 0..63
                int sl = (c & 7) ^ (row & 7);            // inverse-swizzled source slot
                int koff = k0 + sl * 8;
                const unsigned short* srcp;
                if (region == 0) {
                    int ar = m0 + row; ar = ar < N_NODES ? ar : N_NODES - 1;
                    srcp = A + (size_t)ar * DIM + koff;
                } else {
                    srcp = Bt + (size_t)(n0 + row) * DIM + koff;
                }
                unsigned short* lb = lds + region * 4096 + ((it & 1) * 256 + (tid & 192)) * 8;
                gl_lds16(srcp, lb);
            }
            asm volatile("s_waitcnt vmcnt(0)" ::: "memory");
            __syncthreads();

#pragma unroll
            for (int ks = 0; ks < 2; ks++) {
                bf16x8 ah[2], bh[2];
#pragma unroll
                for (int tm = 0; tm < 2; tm++) {
                    int row = wm * 32 + tm * 16 + lr;
                    int ph = (ks * 4 + kq) ^ (row & 7);
                    ah[tm] = __builtin_bit_cast(bf16x8,
                        *reinterpret_cast<const short8*>(lds + row * 64 + ph * 8));
                }
#pragma unroll
                for (int tn = 0; tn < 2; tn++) {
                    int col = wn * 32 + tn * 16 + lr;
                    int ph = (ks * 4 + kq) ^ (col & 7);
                    bh[tn] = __builtin_bit_cast(bf16x8,
                        *reinterpret_cast<const short8*>(lds + 4096 + col * 64 + ph * 8));
                }
#pragma unroll
                for (int tm = 0; tm < 2; tm++)
#pragma unroll
                    for (int tn = 0; tn < 2; tn++)
                        acc[tm][tn] = MFMA(ah[tm], bh[tn], acc[tm][tn]);
            }
            if (t < 7) __syncthreads();
        }

#pragma unroll
        for (int tm = 0; tm < 2; tm++)
#pragma unroll
            for (int tn = 0; tn < 2; tn++) {
                int col = n0 + wn * 32 + tn * 16 + lr;
#pragma unroll
                for (int r4 = 0; r4 < 4; r4++) {
                    int row = m0 + wm * 32 + tm * 16 + kq * 4 + r4;
                    if (row < N_NODES) Hout[(size_t)row * DIM + col] = f32_to_bf16(acc[tm][tn][r4]);
                }
            }
    } else {
        // ---- als role ----
        float* wl = (float*)sbuf;   // 8*DIM floats = 16 KB
        for (int i = tid; i < 8 * DIM / 4; i += 256)
            reinterpret_cast<float4*>(wl)[i] = reinterpret_cast<const float4*>(wt)[i];
        __syncthreads();
        int n = (blockIdx.x - GEMM_BLOCKS) * 4 + (tid >> 6);
        if (n >= N_NODES) return;
        int lane = tid & 63;
        short8 xv8 = *reinterpret_cast<const short8*>(A + (size_t)n * DIM + lane * 8);
        float xv[8];
#pragma unroll
        for (int j = 0; j < 8; j++) xv[j] = bf16_to_f32((unsigned short)xv8[j]);
        float p[8] = {0.f, 0.f, 0.f, 0.f, 0.f, 0.f, 0.f, 0.f};
#pragma unroll
        for (int j = 0; j < 8; j++) {
            int k = lane * 8 + j;
#pragma unroll
            for (int v = 0; v < 8; v++) p[v] += xv[j] * wl[v * DIM + k];
        }
#pragma unroll
        for (int off = 1; off < 64; off <<= 1)
#pragma unroll
            for (int v = 0; v < 8; v++) p[v] += __shfl_xor(p[v], off);
        if (lane == 0) {
            float4 s = {p[0], p[2], p[4], p[6]};
            float4 d = {p[1], p[3], p[5], p[7]};
            *reinterpret_cast<float4*>(als + (size_t)n * 4) = s;
            *reinterpret_cast<float4*>(ald + (size_t)n * 4) = d;
        }
    }
}

// ---------------- XCD-column-sliced aggregation ----------------
// block b: slice = b & 7 (rides round-robin block->XCD mapping), nodes (b>>3)*4 + wid.
// Wave = (node v, slice); lane covers ONE column c = slice*64 + lane; hd = slice>>1
// (wave-uniform). Each XCD touches only H cols [slice*64, slice*64+64) -> 2.56 MB,
// L2-resident. Summation order per (node,col) identical to previous rounds.
__global__ __launch_bounds__(256) void k_agg(const int* __restrict__ offsets,
                                             const int* __restrict__ csr_src,
                                             const float* __restrict__ als,
                                             const float* __restrict__ ald,
                                             const unsigned short* __restrict__ H,
                                             const float* __restrict__ bias,
                                             const float* __restrict__ resid_f32,
                                             const unsigned short* __restrict__ resid_b16,
                                             float* __restrict__ out_f32,
                                             unsigned short* __restrict__ out_b16) {
    int b = blockIdx.x;
    int slice = b & 7;
    int v = (b >> 3) * 4 + (threadIdx.x >> 6);
    if (v >= N_NODES) return;
    int lane = threadIdx.x & 63;
    int c = slice * 64 + lane;
    int hd = slice >> 1;

    int beg = offsets[v], deg = offsets[v + 1] - beg;
    float aldh = ald[v * 4 + hd];
    const int* cp = csr_src + beg;
    const unsigned short* Hc = H + c;

    float acc = 0.f, s = 0.f;
    int i = 0;
    for (; i + 8 <= deg; i += 8) {
        int u[8];
#pragma unroll
        for (int j = 0; j < 8; j++) u[j] = cp[i + j];
        float e[8];
#pragma unroll
        for (int j = 0; j < 8; j++) e[j] = als[u[j] * 4 + hd];
        unsigned short hv[8];
#pragma unroll
        for (int j = 0; j < 8; j++) hv[j] = Hc[(size_t)u[j] * DIM];
#pragma unroll
        for (int j = 0; j < 8; j++) {
            float sc = e[j] + aldh;
            sc = fmaxf(sc, NEG_SLOPE * sc);
            float w = __expf(sc);
            s += w;
            acc += w * bf16_to_f32(hv[j]);
        }
    }
    for (; i < deg; i++) {
        int u0 = cp[i];
        float e0 = als[u0 * 4 + hd];
        unsigned short h0 = Hc[(size_t)u0 * DIM];
        float sc = e0 + aldh;
        sc = fmaxf(sc, NEG_SLOPE * sc);
        float w = __expf(sc);
        s += w;
        acc += w * bf16_to_f32(h0);
    }

    float inv = deg > 0 ? 1.0f / s : 0.f;
    float t = acc * inv + bias[c];
    float o = t > 0.f ? t : expm1f(t);
    o += resid_f32 ? resid_f32[(size_t)v * DIM + c]
                   : bf16_to_f32(resid_b16[(size_t)v * DIM + c]);
    if (out_f32) out_f32[(size_t)v * DIM + c] = o;
    if (out_b16) out_b16[(size_t)v * DIM + c] = f32_to_bf16(o);
}

extern "C" void kernel_launch(void* const* d_in, const int* in_sizes, int n_in,
                              void* d_out, int out_size, void* d_ws, size_t ws_size,
                              hipStream_t stream) {
    const float* x = (const float*)d_in[0];
    const int* ei = (const int*)d_in[1];
    const int* src = ei;
    const int* dst = ei + N_EDGES;
    const float* W1 = (const float*)d_in[5];
    const float* a1 = (const float*)d_in[6];
    const float* b1 = (const float*)d_in[7];
    const float* W2 = (const float*)d_in[8];
    const float* a2 = (const float*)d_in[9];
    const float* b2 = (const float*)d_in[10];

    char* ws = (char*)d_ws;
    size_t off = 0;
    auto alloc = [&](size_t bytes) -> void* {
        void* p = ws + off;
        off += (bytes + 255) & ~(size_t)255;
        return p;
    };
    unsigned short* xb   = (unsigned short*)alloc((size_t)N_NODES * DIM * 2);  // x bf16, then x1 bf16
    unsigned short* h    = (unsigned short*)alloc((size_t)N_NODES * DIM * 2);
    float* als           = (float*)alloc((size_t)N_NODES * 8 * 4);  // als | ald contiguous
    float* ald           = als + (size_t)N_NODES * 4;
    unsigned short* B1   = (unsigned short*)alloc((size_t)DIM * DIM * 2);
    unsigned short* B2   = (unsigned short*)alloc((size_t)DIM * DIM * 2);
    float* wt1           = (float*)alloc((size_t)8 * DIM * 4);
    float* wt2           = (float*)alloc((size_t)8 * DIM * 4);
    int* offsets         = (int*)alloc((size_t)(N_NODES + 1) * 4);
    int* cursor          = (int*)alloc((size_t)N_NODES * 4);
    int* counts          = (int*)alloc((size_t)N_NODES * 4);
    int* csr_src         = (int*)alloc((size_t)N_EDGES * 4);

    const int EB = (N_EDGES + 255) / 256;   // 1250

    // prologue: zero counts, then fused cast/transW/wtilde/hist, scan, fill
    hipMemsetAsync(counts, 0, (size_t)N_NODES * 4, stream);
    k_prep<<<5288 + EB, 256, 0, stream>>>(x, xb, W1, B1, W2, B2, a1, wt1, a2, wt2, dst, counts);
    k_scan<<<1, 1024, 0, stream>>>(counts, offsets, cursor);
    k_fill<<<EB, 256, 0, stream>>>(src, dst, cursor, csr_src);

    const int FUSED_BLOCKS = GEMM_BLOCKS + ALS_BLOCKS;   // 7504
    const int AGG_BLOCKS = 8 * ((N_NODES + 3) / 4);      // 40000: (node-group, slice)

    // ---- layer 1 ----
    k_gemm_als<<<FUSED_BLOCKS, 256, 0, stream>>>(xb, B1, h, wt1, als, ald);
    // resid = x (f32); output bf16 x1 into xb (k_agg doesn't read xb)
    k_agg<<<AGG_BLOCKS, 256, 0, stream>>>(offsets, csr_src, als, ald, h, b1,
                                          x, nullptr, nullptr, xb);

    // ---- layer 2 ----
    k_gemm_als<<<FUSED_BLOCKS, 256, 0, stream>>>(xb, B2, h, wt2, als, ald);
    // resid = x1 (bf16); output f32 d_out
    k_agg<<<AGG_BLOCKS, 256, 0, stream>>>(offsets, csr_src, als, ald, h, b2,
                                          nullptr, xb, (float*)d_out, nullptr);
}

// Round 14
// 366.812 us; speedup vs baseline: 1.0424x; 1.0424x over previous
//
#include <hip/hip_runtime.h>
#include <hip/hip_bf16.h>
#include <math.h>

#define N_NODES 20000
#define N_EDGES 320000
#define DIM 512
#define HEADS 4
#define DHEAD 128
#define NEG_SLOPE 0.2f
#define BM 64
#define BN 64
#define BK 64
#define GEMM_BLOCKS 2504   // 313 * 8
#define ALS_BLOCKS 5000    // 4 nodes per block

typedef __attribute__((ext_vector_type(8))) short short8;
typedef __attribute__((ext_vector_type(8))) __bf16 bf16x8;
typedef __attribute__((ext_vector_type(4))) float f32x4;

static __device__ __forceinline__ unsigned short f32_to_bf16(float f) {
    union { float f; unsigned u; } v; v.f = f;
    unsigned u = v.u;
    u += 0x7FFFu + ((u >> 16) & 1u);   // round-to-nearest-even
    return (unsigned short)(u >> 16);
}
static __device__ __forceinline__ float bf16_to_f32(unsigned short s) {
    union { unsigned u; float f; } v; v.u = ((unsigned)s) << 16;
    return v.f;
}
static __device__ __forceinline__ float bits_f32(unsigned u) {
    union { unsigned u; float f; } v; v.u = u;
    return v.f;
}

static __device__ __forceinline__ void gl_lds16(const unsigned short* g, unsigned short* l) {
    __builtin_amdgcn_global_load_lds(
        (const __attribute__((address_space(1))) unsigned int*)g,
        (__attribute__((address_space(3))) unsigned int*)l, 16, 0, 0);
}

// ---------------- fused prologue: cast | transW x2 | wtilde x2 | hist ----------------
static __device__ __forceinline__ void do_cast(const float* in, unsigned short* out, int i) {
    const float4* p = reinterpret_cast<const float4*>(in) + (size_t)i * 2;
    float4 a = p[0], b = p[1];
    short8 o;
    o[0] = (short)f32_to_bf16(a.x); o[1] = (short)f32_to_bf16(a.y);
    o[2] = (short)f32_to_bf16(a.z); o[3] = (short)f32_to_bf16(a.w);
    o[4] = (short)f32_to_bf16(b.x); o[5] = (short)f32_to_bf16(b.y);
    o[6] = (short)f32_to_bf16(b.z); o[7] = (short)f32_to_bf16(b.w);
    *reinterpret_cast<short8*>(out + (size_t)i * 8) = o;
}
static __device__ __forceinline__ void do_transW(const float* W, unsigned short* Bt, int id) {
    int col = id >> 6;
    int kg = id & 63;
    int h = col >> 7;
    int f = col & 127;
    short8 o;
#pragma unroll
    for (int j = 0; j < 8; j++) {
        int k = kg * 8 + j;
        o[j] = (short)f32_to_bf16(W[(size_t)h * DIM * DHEAD + (size_t)k * DHEAD + f]);
    }
    *reinterpret_cast<short8*>(Bt + (size_t)col * DIM + kg * 8) = o;
}
static __device__ __forceinline__ void do_wtilde(const float* W, const float* a, float* wt, int id) {
    int v = id >> 9, k = id & 511;
    int h = v >> 1, sd = v & 1;
    const float* Wr = W + ((size_t)h * DIM + k) * DHEAD;
    const float* av = a + h * 2 * DHEAD + sd * DHEAD;
    float s = 0.f;
#pragma unroll 4
    for (int f = 0; f < DHEAD; f++) s += Wr[f] * av[f];
    wt[(size_t)v * DIM + k] = s;
}

__global__ void k_prep(const float* __restrict__ x, unsigned short* __restrict__ xb,
                       const float* __restrict__ W1, unsigned short* __restrict__ B1,
                       const float* __restrict__ W2, unsigned short* __restrict__ B2,
                       const float* __restrict__ a1, float* __restrict__ wt1,
                       const float* __restrict__ a2, float* __restrict__ wt2,
                       const int* __restrict__ dst, int* __restrict__ counts) {
    int b = blockIdx.x, tid = threadIdx.x;
    if (b < 5000) {
        do_cast(x, xb, b * 256 + tid);
    } else if (b < 5128) {
        do_transW(W1, B1, (b - 5000) * 256 + tid);
    } else if (b < 5256) {
        do_transW(W2, B2, (b - 5128) * 256 + tid);
    } else if (b < 5272) {
        do_wtilde(W1, a1, wt1, (b - 5256) * 256 + tid);
    } else if (b < 5288) {
        do_wtilde(W2, a2, wt2, (b - 5272) * 256 + tid);
    } else {
        int e = (b - 5288) * 256 + tid;
        if (e < N_EDGES) atomicAdd(&counts[dst[e]], 1);
    }
}

// ---------------- CSR build + degree histogram for node permutation ----------------
__global__ void k_scan(const int* __restrict__ counts, int* __restrict__ offsets,
                       int* __restrict__ cursor, int* __restrict__ degcur) {
    __shared__ int lds[1024];
    __shared__ int degh[64];
    int t = threadIdx.x;
    if (t < 64) degh[t] = 0;
    __syncthreads();
    const int CH = (N_NODES + 1023) / 1024;   // 20
    int base = t * CH;
    int sum = 0;
    for (int j = 0; j < CH; j++) {
        int i = base + j;
        if (i < N_NODES) {
            int c = counts[i];
            sum += c;
            atomicAdd(&degh[c < 63 ? c : 63], 1);
        }
    }
    lds[t] = sum;
    __syncthreads();
    for (int off = 1; off < 1024; off <<= 1) {
        int other = (t >= off) ? lds[t - off] : 0;
        __syncthreads();
        lds[t] += other;
        __syncthreads();
    }
    int excl = lds[t] - sum;
    int run = excl;
    for (int j = 0; j < CH; j++) {
        int i = base + j;
        if (i < N_NODES) {
            offsets[i] = run;
            cursor[i] = run;
            run += counts[i];
        }
    }
    if (t == 0) {
        offsets[N_NODES] = N_EDGES;
        int r = 0;
        for (int d = 0; d < 64; d++) { degcur[d] = r; r += degh[d]; }
    }
}

__global__ void k_fill(const int* __restrict__ src, const int* __restrict__ dst,
                       int* __restrict__ cursor, int* __restrict__ csr_src) {
    int e = blockIdx.x * blockDim.x + threadIdx.x;
    if (e >= N_EDGES) return;
    int d = dst[e];
    int p = atomicAdd(&cursor[d], 1);
    csr_src[p] = src[e];
}

// scatter nodes into degree-sorted permutation (bin order; order within bin arbitrary)
__global__ void k_permfill(const int* __restrict__ counts, int* __restrict__ degcur,
                           int* __restrict__ perm) {
    int n = blockIdx.x * blockDim.x + threadIdx.x;
    if (n >= N_NODES) return;
    int d = counts[n];
    d = d < 63 ? d : 63;
    int p = atomicAdd(&degcur[d], 1);
    perm[p] = n;
}

// ---------------- fused GEMM + attention logits (independent roles, shared 16KB LDS) ----------
#define MFMA(a, b, c) __builtin_amdgcn_mfma_f32_16x16x32_bf16(a, b, c, 0, 0, 0)

__global__ __launch_bounds__(256, 8) void k_gemm_als(const unsigned short* __restrict__ A,
                                                     const unsigned short* __restrict__ Bt,
                                                     unsigned short* __restrict__ Hout,
                                                     const float* __restrict__ wt,
                                                     float* __restrict__ als,
                                                     float* __restrict__ ald) {
    __shared__ __align__(16) char sbuf[16384];
    const int tid = threadIdx.x;

    if (blockIdx.x < GEMM_BLOCKS) {
        unsigned short* lds = (unsigned short*)sbuf;
        // bijective XCD swizzle: 2504 = 8 * 313 exactly
        const int orig = blockIdx.x;
        const int wgid = (orig & 7) * 313 + (orig >> 3);
        const int mb = wgid >> 3, nb = wgid & 7;
        const int m0 = mb * BM, n0 = nb * BN;
        const int lane = tid & 63, wid = tid >> 6;
        const int wm = wid >> 1, wn = wid & 1;
        const int lr = lane & 15, kq = lane >> 4;

        f32x4 acc[2][2];
#pragma unroll
        for (int i = 0; i < 2; i++)
#pragma unroll
            for (int j = 0; j < 2; j++) acc[i][j] = (f32x4){0.f, 0.f, 0.f, 0.f};

#pragma unroll 1
        for (int t = 0; t < 8; t++) {
            const int k0 = t * BK;
#pragma unroll
            for (int it = 0; it < 4; it++) {
                const int region = it >> 1;              // 0=A 1=B
                int c = (it & 1) * 256 + tid;            // 0..511
                int row = c >> 3;                        // 0..63
                int sl = (c & 7) ^ (row & 7);            // inverse-swizzled source slot
                int koff = k0 + sl * 8;
                const unsigned short* srcp;
                if (region == 0) {
                    int ar = m0 + row; ar = ar < N_NODES ? ar : N_NODES - 1;
                    srcp = A + (size_t)ar * DIM + koff;
                } else {
                    srcp = Bt + (size_t)(n0 + row) * DIM + koff;
                }
                unsigned short* lb = lds + region * 4096 + ((it & 1) * 256 + (tid & 192)) * 8;
                gl_lds16(srcp, lb);
            }
            asm volatile("s_waitcnt vmcnt(0)" ::: "memory");
            __syncthreads();

#pragma unroll
            for (int ks = 0; ks < 2; ks++) {
                bf16x8 ah[2], bh[2];
#pragma unroll
                for (int tm = 0; tm < 2; tm++) {
                    int row = wm * 32 + tm * 16 + lr;
                    int ph = (ks * 4 + kq) ^ (row & 7);
                    ah[tm] = __builtin_bit_cast(bf16x8,
                        *reinterpret_cast<const short8*>(lds + row * 64 + ph * 8));
                }
#pragma unroll
                for (int tn = 0; tn < 2; tn++) {
                    int col = wn * 32 + tn * 16 + lr;
                    int ph = (ks * 4 + kq) ^ (col & 7);
                    bh[tn] = __builtin_bit_cast(bf16x8,
                        *reinterpret_cast<const short8*>(lds + 4096 + col * 64 + ph * 8));
                }
#pragma unroll
                for (int tm = 0; tm < 2; tm++)
#pragma unroll
                    for (int tn = 0; tn < 2; tn++)
                        acc[tm][tn] = MFMA(ah[tm], bh[tn], acc[tm][tn]);
            }
            if (t < 7) __syncthreads();
        }

#pragma unroll
        for (int tm = 0; tm < 2; tm++)
#pragma unroll
            for (int tn = 0; tn < 2; tn++) {
                int col = n0 + wn * 32 + tn * 16 + lr;
#pragma unroll
                for (int r4 = 0; r4 < 4; r4++) {
                    int row = m0 + wm * 32 + tm * 16 + kq * 4 + r4;
                    if (row < N_NODES) Hout[(size_t)row * DIM + col] = f32_to_bf16(acc[tm][tn][r4]);
                }
            }
    } else {
        // ---- als role ----
        float* wl = (float*)sbuf;   // 8*DIM floats = 16 KB
        for (int i = tid; i < 8 * DIM / 4; i += 256)
            reinterpret_cast<float4*>(wl)[i] = reinterpret_cast<const float4*>(wt)[i];
        __syncthreads();
        int n = (blockIdx.x - GEMM_BLOCKS) * 4 + (tid >> 6);
        if (n >= N_NODES) return;
        int lane = tid & 63;
        short8 xv8 = *reinterpret_cast<const short8*>(A + (size_t)n * DIM + lane * 8);
        float xv[8];
#pragma unroll
        for (int j = 0; j < 8; j++) xv[j] = bf16_to_f32((unsigned short)xv8[j]);
        float p[8] = {0.f, 0.f, 0.f, 0.f, 0.f, 0.f, 0.f, 0.f};
#pragma unroll
        for (int j = 0; j < 8; j++) {
            int k = lane * 8 + j;
#pragma unroll
            for (int v = 0; v < 8; v++) p[v] += xv[j] * wl[v * DIM + k];
        }
#pragma unroll
        for (int off = 1; off < 64; off <<= 1)
#pragma unroll
            for (int v = 0; v < 8; v++) p[v] += __shfl_xor(p[v], off);
        if (lane == 0) {
            float4 s = {p[0], p[2], p[4], p[6]};
            float4 d = {p[1], p[3], p[5], p[7]};
            *reinterpret_cast<float4*>(als + (size_t)n * 4) = s;
            *reinterpret_cast<float4*>(ald + (size_t)n * 4) = d;
        }
    }
}

// ---------------- XCD-column-sliced aggregation, 4 cols/lane, deg-sorted 4-node waves ----------
// block b: slice = b & 7 (rides round-robin block->XCD mapping: 2.56 MB H-slice per XCD L2).
// 256 threads = 4 waves; wave = 4 groups of 16 lanes; group handles node perm[...] with
// lane covering 4 cols at c0 = slice*64 + gl*4 (uint2 = 8B loads). Degree-sorted perm makes
// the 4 nodes per wave near-equal deg -> maxdeg predicated loop wastes ~nothing.
__global__ __launch_bounds__(256) void k_agg(const int* __restrict__ offsets,
                                             const int* __restrict__ csr_src,
                                             const int* __restrict__ perm,
                                             const float* __restrict__ als,
                                             const float* __restrict__ ald,
                                             const unsigned short* __restrict__ H,
                                             const float* __restrict__ bias,
                                             const float* __restrict__ resid_f32,
                                             const unsigned short* __restrict__ resid_b16,
                                             float* __restrict__ out_f32,
                                             unsigned short* __restrict__ out_b16) {
    int b = blockIdx.x;
    int slice = b & 7;
    int wid = threadIdx.x >> 6;
    int lane = threadIdx.x & 63;
    int group = lane >> 4;
    int gl = lane & 15;
    int v = perm[(b >> 3) * 16 + wid * 4 + group];   // 20000 % 16 == 0: always valid
    int c0 = slice * 64 + gl * 4;
    int hd = slice >> 1;

    int beg = offsets[v];
    int deg = offsets[v + 1] - beg;
    float aldh = ald[v * 4 + hd];

    int m1 = max(deg, __shfl_xor(deg, 16));
    int maxdeg = max(m1, __shfl_xor(m1, 32));

    const unsigned short* Hc = H + c0;
    float a0 = 0.f, a1 = 0.f, a2 = 0.f, a3 = 0.f, s = 0.f;
    for (int i = 0; i < maxdeg; i++) {
        bool valid = i < deg;
        int idx = beg + (valid ? i : 0);
        idx = idx < N_EDGES ? idx : N_EDGES - 1;     // deg==0 tail safety
        int u = csr_src[idx];                        // broadcast within group
        float e = als[u * 4 + hd];                   // broadcast within group
        uint2 hq = *reinterpret_cast<const uint2*>(Hc + (size_t)u * DIM);  // 128B/group
        float sc = e + aldh;
        sc = fmaxf(sc, NEG_SLOPE * sc);
        float w = valid ? __expf(sc) : 0.f;
        s += w;
        a0 += w * bits_f32(hq.x << 16);
        a1 += w * bits_f32(hq.x & 0xFFFF0000u);
        a2 += w * bits_f32(hq.y << 16);
        a3 += w * bits_f32(hq.y & 0xFFFF0000u);
    }

    float inv = deg > 0 ? 1.0f / s : 0.f;
    float4 bv = *reinterpret_cast<const float4*>(bias + c0);
    float o0 = a0 * inv + bv.x;
    float o1 = a1 * inv + bv.y;
    float o2 = a2 * inv + bv.z;
    float o3 = a3 * inv + bv.w;
    o0 = o0 > 0.f ? o0 : expm1f(o0);
    o1 = o1 > 0.f ? o1 : expm1f(o1);
    o2 = o2 > 0.f ? o2 : expm1f(o2);
    o3 = o3 > 0.f ? o3 : expm1f(o3);
    if (resid_f32) {
        float4 rv = *reinterpret_cast<const float4*>(resid_f32 + (size_t)v * DIM + c0);
        o0 += rv.x; o1 += rv.y; o2 += rv.z; o3 += rv.w;
    } else {
        ushort4 rv = *reinterpret_cast<const ushort4*>(resid_b16 + (size_t)v * DIM + c0);
        o0 += bf16_to_f32(rv.x); o1 += bf16_to_f32(rv.y);
        o2 += bf16_to_f32(rv.z); o3 += bf16_to_f32(rv.w);
    }
    if (out_f32) {
        float4 ov = {o0, o1, o2, o3};
        *reinterpret_cast<float4*>(out_f32 + (size_t)v * DIM + c0) = ov;
    }
    if (out_b16) {
        ushort4 ob = {f32_to_bf16(o0), f32_to_bf16(o1), f32_to_bf16(o2), f32_to_bf16(o3)};
        *reinterpret_cast<ushort4*>(out_b16 + (size_t)v * DIM + c0) = ob;
    }
}

extern "C" void kernel_launch(void* const* d_in, const int* in_sizes, int n_in,
                              void* d_out, int out_size, void* d_ws, size_t ws_size,
                              hipStream_t stream) {
    const float* x = (const float*)d_in[0];
    const int* ei = (const int*)d_in[1];
    const int* src = ei;
    const int* dst = ei + N_EDGES;
    const float* W1 = (const float*)d_in[5];
    const float* a1 = (const float*)d_in[6];
    const float* b1 = (const float*)d_in[7];
    const float* W2 = (const float*)d_in[8];
    const float* a2 = (const float*)d_in[9];
    const float* b2 = (const float*)d_in[10];

    char* ws = (char*)d_ws;
    size_t off = 0;
    auto alloc = [&](size_t bytes) -> void* {
        void* p = ws + off;
        off += (bytes + 255) & ~(size_t)255;
        return p;
    };
    unsigned short* xb   = (unsigned short*)alloc((size_t)N_NODES * DIM * 2);  // x bf16, then x1 bf16
    unsigned short* h    = (unsigned short*)alloc((size_t)N_NODES * DIM * 2);
    float* als           = (float*)alloc((size_t)N_NODES * 8 * 4);  // als | ald contiguous
    float* ald           = als + (size_t)N_NODES * 4;
    unsigned short* B1   = (unsigned short*)alloc((size_t)DIM * DIM * 2);
    unsigned short* B2   = (unsigned short*)alloc((size_t)DIM * DIM * 2);
    float* wt1           = (float*)alloc((size_t)8 * DIM * 4);
    float* wt2           = (float*)alloc((size_t)8 * DIM * 4);
    int* offsets         = (int*)alloc((size_t)(N_NODES + 1) * 4);
    int* cursor          = (int*)alloc((size_t)N_NODES * 4);
    int* counts          = (int*)alloc((size_t)N_NODES * 4);
    int* csr_src         = (int*)alloc((size_t)N_EDGES * 4);
    int* degcur          = (int*)alloc((size_t)64 * 4);
    int* perm            = (int*)alloc((size_t)N_NODES * 4);

    const int EB = (N_EDGES + 255) / 256;   // 1250

    // prologue: zero counts, fused cast/transW/wtilde/hist, scan(+deg histogram), fill, perm
    hipMemsetAsync(counts, 0, (size_t)N_NODES * 4, stream);
    k_prep<<<5288 + EB, 256, 0, stream>>>(x, xb, W1, B1, W2, B2, a1, wt1, a2, wt2, dst, counts);
    k_scan<<<1, 1024, 0, stream>>>(counts, offsets, cursor, degcur);
    k_fill<<<EB, 256, 0, stream>>>(src, dst, cursor, csr_src);
    k_permfill<<<(N_NODES + 255) / 256, 256, 0, stream>>>(counts, degcur, perm);

    const int FUSED_BLOCKS = GEMM_BLOCKS + ALS_BLOCKS;   // 7504
    const int AGG_BLOCKS = 8 * (N_NODES / 16);           // 10000: (node-group-of-16, slice)

    // ---- layer 1 ----
    k_gemm_als<<<FUSED_BLOCKS, 256, 0, stream>>>(xb, B1, h, wt1, als, ald);
    // resid = x (f32); output bf16 x1 into xb (k_agg doesn't read xb)
    k_agg<<<AGG_BLOCKS, 256, 0, stream>>>(offsets, csr_src, perm, als, ald, h, b1,
                                          x, nullptr, nullptr, xb);

    // ---- layer 2 ----
    k_gemm_als<<<FUSED_BLOCKS, 256, 0, stream>>>(xb, B2, h, wt2, als, ald);
    // resid = x1 (bf16); output f32 d_out
    k_agg<<<AGG_BLOCKS, 256, 0, stream>>>(offsets, csr_src, perm, als, ald, h, b2,
                                          nullptr, xb, (float*)d_out, nullptr);
}

// Round 15
// 267.164 us; speedup vs baseline: 1.4312x; 1.3730x over previous
//
#include <hip/hip_runtime.h>
#include <hip/hip_bf16.h>
#include <math.h>

#define N_NODES 20000
#define N_EDGES 320000
#define DIM 512
#define HEADS 4
#define DHEAD 128
#define NEG_SLOPE 0.2f
#define BM 64
#define BN 64
#define BK 64
#define GEMM_BLOCKS 2504   // 313 * 8
#define ALS_BLOCKS 5000    // 4 nodes per block

typedef __attribute__((ext_vector_type(8))) short short8;
typedef __attribute__((ext_vector_type(8))) __bf16 bf16x8;
typedef __attribute__((ext_vector_type(4))) float f32x4;

static __device__ __forceinline__ unsigned short f32_to_bf16(float f) {
    union { float f; unsigned u; } v; v.f = f;
    unsigned u = v.u;
    u += 0x7FFFu + ((u >> 16) & 1u);   // round-to-nearest-even
    return (unsigned short)(u >> 16);
}
static __device__ __forceinline__ float bf16_to_f32(unsigned short s) {
    union { unsigned u; float f; } v; v.u = ((unsigned)s) << 16;
    return v.f;
}
static __device__ __forceinline__ float bits_f32(unsigned u) {
    union { unsigned u; float f; } v; v.u = u;
    return v.f;
}

static __device__ __forceinline__ void gl_lds16(const unsigned short* g, unsigned short* l) {
    __builtin_amdgcn_global_load_lds(
        (const __attribute__((address_space(1))) unsigned int*)g,
        (__attribute__((address_space(3))) unsigned int*)l, 16, 0, 0);
}

// ---------------- fused prologue: cast | transW x2 | wtilde x2 | hist ----------------
static __device__ __forceinline__ void do_cast(const float* in, unsigned short* out, int i) {
    const float4* p = reinterpret_cast<const float4*>(in) + (size_t)i * 2;
    float4 a = p[0], b = p[1];
    short8 o;
    o[0] = (short)f32_to_bf16(a.x); o[1] = (short)f32_to_bf16(a.y);
    o[2] = (short)f32_to_bf16(a.z); o[3] = (short)f32_to_bf16(a.w);
    o[4] = (short)f32_to_bf16(b.x); o[5] = (short)f32_to_bf16(b.y);
    o[6] = (short)f32_to_bf16(b.z); o[7] = (short)f32_to_bf16(b.w);
    *reinterpret_cast<short8*>(out + (size_t)i * 8) = o;
}
static __device__ __forceinline__ void do_transW(const float* W, unsigned short* Bt, int id) {
    int col = id >> 6;
    int kg = id & 63;
    int h = col >> 7;
    int f = col & 127;
    short8 o;
#pragma unroll
    for (int j = 0; j < 8; j++) {
        int k = kg * 8 + j;
        o[j] = (short)f32_to_bf16(W[(size_t)h * DIM * DHEAD + (size_t)k * DHEAD + f]);
    }
    *reinterpret_cast<short8*>(Bt + (size_t)col * DIM + kg * 8) = o;
}
static __device__ __forceinline__ void do_wtilde(const float* W, const float* a, float* wt, int id) {
    int v = id >> 9, k = id & 511;
    int h = v >> 1, sd = v & 1;
    const float* Wr = W + ((size_t)h * DIM + k) * DHEAD;
    const float* av = a + h * 2 * DHEAD + sd * DHEAD;
    float s = 0.f;
#pragma unroll 4
    for (int f = 0; f < DHEAD; f++) s += Wr[f] * av[f];
    wt[(size_t)v * DIM + k] = s;
}

__global__ void k_prep(const float* __restrict__ x, unsigned short* __restrict__ xb,
                       const float* __restrict__ W1, unsigned short* __restrict__ B1,
                       const float* __restrict__ W2, unsigned short* __restrict__ B2,
                       const float* __restrict__ a1, float* __restrict__ wt1,
                       const float* __restrict__ a2, float* __restrict__ wt2,
                       const int* __restrict__ dst, int* __restrict__ counts) {
    int b = blockIdx.x, tid = threadIdx.x;
    if (b < 5000) {
        do_cast(x, xb, b * 256 + tid);
    } else if (b < 5128) {
        do_transW(W1, B1, (b - 5000) * 256 + tid);
    } else if (b < 5256) {
        do_transW(W2, B2, (b - 5128) * 256 + tid);
    } else if (b < 5272) {
        do_wtilde(W1, a1, wt1, (b - 5256) * 256 + tid);
    } else if (b < 5288) {
        do_wtilde(W2, a2, wt2, (b - 5272) * 256 + tid);
    } else {
        int e = (b - 5288) * 256 + tid;
        if (e < N_EDGES) atomicAdd(&counts[dst[e]], 1);
    }
}

// ---------------- CSR build ----------------
__global__ void k_scan(const int* __restrict__ counts, int* __restrict__ offsets,
                       int* __restrict__ cursor) {
    __shared__ int lds[1024];
    int t = threadIdx.x;
    const int CH = (N_NODES + 1023) / 1024;   // 20
    int base = t * CH;
    int sum = 0;
    for (int j = 0; j < CH; j++) {
        int i = base + j;
        if (i < N_NODES) sum += counts[i];
    }
    lds[t] = sum;
    __syncthreads();
    for (int off = 1; off < 1024; off <<= 1) {
        int other = (t >= off) ? lds[t - off] : 0;
        __syncthreads();
        lds[t] += other;
        __syncthreads();
    }
    int excl = lds[t] - sum;
    int run = excl;
    for (int j = 0; j < CH; j++) {
        int i = base + j;
        if (i < N_NODES) {
            offsets[i] = run;
            cursor[i] = run;
            run += counts[i];
        }
    }
    if (t == 0) offsets[N_NODES] = N_EDGES;
}

__global__ void k_fill(const int* __restrict__ src, const int* __restrict__ dst,
                       int* __restrict__ cursor, int* __restrict__ csr_src) {
    int e = blockIdx.x * blockDim.x + threadIdx.x;
    if (e >= N_EDGES) return;
    int d = dst[e];
    int p = atomicAdd(&cursor[d], 1);
    csr_src[p] = src[e];
}

// ---------------- fused GEMM + attention logits (independent roles, shared 16KB LDS) ----------
#define MFMA(a, b, c) __builtin_amdgcn_mfma_f32_16x16x32_bf16(a, b, c, 0, 0, 0)

__global__ __launch_bounds__(256, 8) void k_gemm_als(const unsigned short* __restrict__ A,
                                                     const unsigned short* __restrict__ Bt,
                                                     unsigned short* __restrict__ Hout,
                                                     const float* __restrict__ wt,
                                                     float* __restrict__ als,
                                                     float* __restrict__ ald) {
    __shared__ __align__(16) char sbuf[16384];
    const int tid = threadIdx.x;

    if (blockIdx.x < GEMM_BLOCKS) {
        unsigned short* lds = (unsigned short*)sbuf;
        // bijective XCD swizzle: 2504 = 8 * 313 exactly
        const int orig = blockIdx.x;
        const int wgid = (orig & 7) * 313 + (orig >> 3);
        const int mb = wgid >> 3, nb = wgid & 7;
        const int m0 = mb * BM, n0 = nb * BN;
        const int lane = tid & 63, wid = tid >> 6;
        const int wm = wid >> 1, wn = wid & 1;
        const int lr = lane & 15, kq = lane >> 4;

        f32x4 acc[2][2];
#pragma unroll
        for (int i = 0; i < 2; i++)
#pragma unroll
            for (int j = 0; j < 2; j++) acc[i][j] = (f32x4){0.f, 0.f, 0.f, 0.f};

#pragma unroll 1
        for (int t = 0; t < 8; t++) {
            const int k0 = t * BK;
#pragma unroll
            for (int it = 0; it < 4; it++) {
                const int region = it >> 1;              // 0=A 1=B
                int c = (it & 1) * 256 + tid;            // 0..511
                int row = c >> 3;                        // 0..63
                int sl = (c & 7) ^ (row & 7);            // inverse-swizzled source slot
                int koff = k0 + sl * 8;
                const unsigned short* srcp;
                if (region == 0) {
                    int ar = m0 + row; ar = ar < N_NODES ? ar : N_NODES - 1;
                    srcp = A + (size_t)ar * DIM + koff;
                } else {
                    srcp = Bt + (size_t)(n0 + row) * DIM + koff;
                }
                unsigned short* lb = lds + region * 4096 + ((it & 1) * 256 + (tid & 192)) * 8;
                gl_lds16(srcp, lb);
            }
            asm volatile("s_waitcnt vmcnt(0)" ::: "memory");
            __syncthreads();

#pragma unroll
            for (int ks = 0; ks < 2; ks++) {
                bf16x8 ah[2], bh[2];
#pragma unroll
                for (int tm = 0; tm < 2; tm++) {
                    int row = wm * 32 + tm * 16 + lr;
                    int ph = (ks * 4 + kq) ^ (row & 7);
                    ah[tm] = __builtin_bit_cast(bf16x8,
                        *reinterpret_cast<const short8*>(lds + row * 64 + ph * 8));
                }
#pragma unroll
                for (int tn = 0; tn < 2; tn++) {
                    int col = wn * 32 + tn * 16 + lr;
                    int ph = (ks * 4 + kq) ^ (col & 7);
                    bh[tn] = __builtin_bit_cast(bf16x8,
                        *reinterpret_cast<const short8*>(lds + 4096 + col * 64 + ph * 8));
                }
#pragma unroll
                for (int tm = 0; tm < 2; tm++)
#pragma unroll
                    for (int tn = 0; tn < 2; tn++)
                        acc[tm][tn] = MFMA(ah[tm], bh[tn], acc[tm][tn]);
            }
            if (t < 7) __syncthreads();
        }

#pragma unroll
        for (int tm = 0; tm < 2; tm++)
#pragma unroll
            for (int tn = 0; tn < 2; tn++) {
                int col = n0 + wn * 32 + tn * 16 + lr;
#pragma unroll
                for (int r4 = 0; r4 < 4; r4++) {
                    int row = m0 + wm * 32 + tm * 16 + kq * 4 + r4;
                    if (row < N_NODES) Hout[(size_t)row * DIM + col] = f32_to_bf16(acc[tm][tn][r4]);
                }
            }
    } else {
        // ---- als role ----
        float* wl = (float*)sbuf;   // 8*DIM floats = 16 KB
        for (int i = tid; i < 8 * DIM / 4; i += 256)
            reinterpret_cast<float4*>(wl)[i] = reinterpret_cast<const float4*>(wt)[i];
        __syncthreads();
        int n = (blockIdx.x - GEMM_BLOCKS) * 4 + (tid >> 6);
        if (n >= N_NODES) return;
        int lane = tid & 63;
        short8 xv8 = *reinterpret_cast<const short8*>(A + (size_t)n * DIM + lane * 8);
        float xv[8];
#pragma unroll
        for (int j = 0; j < 8; j++) xv[j] = bf16_to_f32((unsigned short)xv8[j]);
        float p[8] = {0.f, 0.f, 0.f, 0.f, 0.f, 0.f, 0.f, 0.f};
#pragma unroll
        for (int j = 0; j < 8; j++) {
            int k = lane * 8 + j;
#pragma unroll
            for (int v = 0; v < 8; v++) p[v] += xv[j] * wl[v * DIM + k];
        }
#pragma unroll
        for (int off = 1; off < 64; off <<= 1)
#pragma unroll
            for (int v = 0; v < 8; v++) p[v] += __shfl_xor(p[v], off);
        if (lane == 0) {
            float4 s = {p[0], p[2], p[4], p[6]};
            float4 d = {p[1], p[3], p[5], p[7]};
            *reinterpret_cast<float4*>(als + (size_t)n * 4) = s;
            *reinterpret_cast<float4*>(ald + (size_t)n * 4) = d;
        }
    }
}

// ---------------- single-pass aggregation: TWO waves per node (best measured layout) ----------
// wave = (node v, half hf); lane covers 4 cols at c0 = hf*256 + lane*4 (uint2 8B loads).
// w = exp(leaky(als[u][hd] + ald[v][hd])); alpha = w / sum(w). |logit| <= ~45 << 88: safe.
#define ACC4(w_, hq)                                                        \
    {                                                                       \
        s += w_;                                                            \
        a0 += w_ * bits_f32((hq).x << 16);                                  \
        a1 += w_ * bits_f32((hq).x & 0xFFFF0000u);                          \
        a2 += w_ * bits_f32((hq).y << 16);                                  \
        a3 += w_ * bits_f32((hq).y & 0xFFFF0000u);                          \
    }

__global__ __launch_bounds__(256) void k_agg(const int* __restrict__ offsets,
                                             const int* __restrict__ csr_src,
                                             const float* __restrict__ als,
                                             const float* __restrict__ ald,
                                             const unsigned short* __restrict__ H,
                                             const float* __restrict__ bias,
                                             const float* __restrict__ resid_f32,
                                             const unsigned short* __restrict__ resid_b16,
                                             float* __restrict__ out_f32,
                                             unsigned short* __restrict__ out_b16) {
    int gw = (blockIdx.x * blockDim.x + threadIdx.x) >> 6;
    if (gw >= N_NODES * 2) return;
    int v = gw >> 1;
    int hf = gw & 1;
    int lane = threadIdx.x & 63;
    int c0 = hf * 256 + lane * 4;
    int hd = c0 >> 7;

    int beg = offsets[v], deg = offsets[v + 1] - beg;
    float aldh = ald[v * 4 + hd];
    const int* cp = csr_src + beg;
    const unsigned short* Hc = H + c0;

    float a0 = 0.f, a1 = 0.f, a2 = 0.f, a3 = 0.f, s = 0.f;
    int i = 0;
    for (; i + 8 <= deg; i += 8) {
        int u[8];
#pragma unroll
        for (int j = 0; j < 8; j++) u[j] = cp[i + j];
        float e[8];
#pragma unroll
        for (int j = 0; j < 8; j++) e[j] = als[u[j] * 4 + hd];
        uint2 hq[8];
#pragma unroll
        for (int j = 0; j < 8; j++)
            hq[j] = *reinterpret_cast<const uint2*>(Hc + (size_t)u[j] * DIM);
#pragma unroll
        for (int j = 0; j < 8; j++) {
            float sc = e[j] + aldh;
            sc = fmaxf(sc, NEG_SLOPE * sc);
            float w = __expf(sc);
            ACC4(w, hq[j]);
        }
    }
    for (; i < deg; i++) {
        int u0 = cp[i];
        float e0 = als[u0 * 4 + hd];
        uint2 h0 = *reinterpret_cast<const uint2*>(Hc + (size_t)u0 * DIM);
        float sc = e0 + aldh;
        sc = fmaxf(sc, NEG_SLOPE * sc);
        float w = __expf(sc);
        ACC4(w, h0);
    }

    float inv = deg > 0 ? 1.0f / s : 0.f;
    float4 bv = *reinterpret_cast<const float4*>(bias + c0);
    float o0 = a0 * inv + bv.x;
    float o1 = a1 * inv + bv.y;
    float o2 = a2 * inv + bv.z;
    float o3 = a3 * inv + bv.w;
    o0 = o0 > 0.f ? o0 : expm1f(o0);
    o1 = o1 > 0.f ? o1 : expm1f(o1);
    o2 = o2 > 0.f ? o2 : expm1f(o2);
    o3 = o3 > 0.f ? o3 : expm1f(o3);
    if (resid_f32) {
        float4 rv = *reinterpret_cast<const float4*>(resid_f32 + (size_t)v * DIM + c0);
        o0 += rv.x; o1 += rv.y; o2 += rv.z; o3 += rv.w;
    } else {
        ushort4 rv = *reinterpret_cast<const ushort4*>(resid_b16 + (size_t)v * DIM + c0);
        o0 += bf16_to_f32(rv.x); o1 += bf16_to_f32(rv.y);
        o2 += bf16_to_f32(rv.z); o3 += bf16_to_f32(rv.w);
    }
    if (out_f32) {
        float4 ov = {o0, o1, o2, o3};
        *reinterpret_cast<float4*>(out_f32 + (size_t)v * DIM + c0) = ov;
    }
    if (out_b16) {
        ushort4 ob = {f32_to_bf16(o0), f32_to_bf16(o1), f32_to_bf16(o2), f32_to_bf16(o3)};
        *reinterpret_cast<ushort4*>(out_b16 + (size_t)v * DIM + c0) = ob;
    }
}

extern "C" void kernel_launch(void* const* d_in, const int* in_sizes, int n_in,
                              void* d_out, int out_size, void* d_ws, size_t ws_size,
                              hipStream_t stream) {
    const float* x = (const float*)d_in[0];
    const int* ei = (const int*)d_in[1];
    const int* src = ei;
    const int* dst = ei + N_EDGES;
    const float* W1 = (const float*)d_in[5];
    const float* a1 = (const float*)d_in[6];
    const float* b1 = (const float*)d_in[7];
    const float* W2 = (const float*)d_in[8];
    const float* a2 = (const float*)d_in[9];
    const float* b2 = (const float*)d_in[10];

    char* ws = (char*)d_ws;
    size_t off = 0;
    auto alloc = [&](size_t bytes) -> void* {
        void* p = ws + off;
        off += (bytes + 255) & ~(size_t)255;
        return p;
    };
    unsigned short* xb   = (unsigned short*)alloc((size_t)N_NODES * DIM * 2);  // x bf16, then x1 bf16
    unsigned short* h    = (unsigned short*)alloc((size_t)N_NODES * DIM * 2);
    float* als           = (float*)alloc((size_t)N_NODES * 8 * 4);  // als | ald contiguous
    float* ald           = als + (size_t)N_NODES * 4;
    unsigned short* B1   = (unsigned short*)alloc((size_t)DIM * DIM * 2);
    unsigned short* B2   = (unsigned short*)alloc((size_t)DIM * DIM * 2);
    float* wt1           = (float*)alloc((size_t)8 * DIM * 4);
    float* wt2           = (float*)alloc((size_t)8 * DIM * 4);
    int* offsets         = (int*)alloc((size_t)(N_NODES + 1) * 4);
    int* cursor          = (int*)alloc((size_t)N_NODES * 4);
    int* counts          = (int*)alloc((size_t)N_NODES * 4);
    int* csr_src         = (int*)alloc((size_t)N_EDGES * 4);

    const int EB = (N_EDGES + 255) / 256;   // 1250

    // prologue: zero counts, then fused cast/transW/wtilde/hist, scan, fill
    hipMemsetAsync(counts, 0, (size_t)N_NODES * 4, stream);
    k_prep<<<5288 + EB, 256, 0, stream>>>(x, xb, W1, B1, W2, B2, a1, wt1, a2, wt2, dst, counts);
    k_scan<<<1, 1024, 0, stream>>>(counts, offsets, cursor);
    k_fill<<<EB, 256, 0, stream>>>(src, dst, cursor, csr_src);

    const int FUSED_BLOCKS = GEMM_BLOCKS + ALS_BLOCKS;   // 7504
    const int AGG_BLOCKS = (N_NODES * 2 + 3) / 4;        // 10000 (2 waves/node)

    // ---- layer 1 ----
    k_gemm_als<<<FUSED_BLOCKS, 256, 0, stream>>>(xb, B1, h, wt1, als, ald);
    // resid = x (f32); output bf16 x1 into xb (k_agg doesn't read xb)
    k_agg<<<AGG_BLOCKS, 256, 0, stream>>>(offsets, csr_src, als, ald, h, b1,
                                          x, nullptr, nullptr, xb);

    // ---- layer 2 ----
    k_gemm_als<<<FUSED_BLOCKS, 256, 0, stream>>>(xb, B2, h, wt2, als, ald);
    // resid = x1 (bf16); output f32 d_out
    k_agg<<<AGG_BLOCKS, 256, 0, stream>>>(offsets, csr_src, als, ald, h, b2,
                                          nullptr, xb, (float*)d_out, nullptr);
}

// Round 16
// 259.247 us; speedup vs baseline: 1.4749x; 1.0305x over previous
//
#include <hip/hip_runtime.h>
#include <hip/hip_bf16.h>
#include <math.h>

#define N_NODES 20000
#define N_EDGES 320000
#define DIM 512
#define HEADS 4
#define DHEAD 128
#define NEG_SLOPE 0.2f
#define BM 64
#define BN 64
#define BK 64
#define GEMM_BLOCKS 2504   // 313 * 8
#define ALS_BLOCKS 5000    // 4 nodes per block

typedef __attribute__((ext_vector_type(8))) short short8;
typedef __attribute__((ext_vector_type(8))) __bf16 bf16x8;
typedef __attribute__((ext_vector_type(4))) float f32x4;

static __device__ __forceinline__ unsigned short f32_to_bf16(float f) {
    union { float f; unsigned u; } v; v.f = f;
    unsigned u = v.u;
    u += 0x7FFFu + ((u >> 16) & 1u);   // round-to-nearest-even
    return (unsigned short)(u >> 16);
}
static __device__ __forceinline__ float bf16_to_f32(unsigned short s) {
    union { unsigned u; float f; } v; v.u = ((unsigned)s) << 16;
    return v.f;
}
static __device__ __forceinline__ float bits_f32(unsigned u) {
    union { unsigned u; float f; } v; v.u = u;
    return v.f;
}

static __device__ __forceinline__ void gl_lds16(const unsigned short* g, unsigned short* l) {
    __builtin_amdgcn_global_load_lds(
        (const __attribute__((address_space(1))) unsigned int*)g,
        (__attribute__((address_space(3))) unsigned int*)l, 16, 0, 0);
}

// ---------------- fused prologue: cast | transW x2 | wtilde x2 | hist ----------------
static __device__ __forceinline__ void do_cast(const float* in, unsigned short* out, int i) {
    const float4* p = reinterpret_cast<const float4*>(in) + (size_t)i * 2;
    float4 a = p[0], b = p[1];
    short8 o;
    o[0] = (short)f32_to_bf16(a.x); o[1] = (short)f32_to_bf16(a.y);
    o[2] = (short)f32_to_bf16(a.z); o[3] = (short)f32_to_bf16(a.w);
    o[4] = (short)f32_to_bf16(b.x); o[5] = (short)f32_to_bf16(b.y);
    o[6] = (short)f32_to_bf16(b.z); o[7] = (short)f32_to_bf16(b.w);
    *reinterpret_cast<short8*>(out + (size_t)i * 8) = o;
}
static __device__ __forceinline__ void do_transW(const float* W, unsigned short* Bt, int id) {
    int col = id >> 6;
    int kg = id & 63;
    int h = col >> 7;
    int f = col & 127;
    short8 o;
#pragma unroll
    for (int j = 0; j < 8; j++) {
        int k = kg * 8 + j;
        o[j] = (short)f32_to_bf16(W[(size_t)h * DIM * DHEAD + (size_t)k * DHEAD + f]);
    }
    *reinterpret_cast<short8*>(Bt + (size_t)col * DIM + kg * 8) = o;
}
static __device__ __forceinline__ void do_wtilde(const float* W, const float* a, float* wt, int id) {
    int v = id >> 9, k = id & 511;
    int h = v >> 1, sd = v & 1;
    const float* Wr = W + ((size_t)h * DIM + k) * DHEAD;
    const float* av = a + h * 2 * DHEAD + sd * DHEAD;
    float s = 0.f;
#pragma unroll 4
    for (int f = 0; f < DHEAD; f++) s += Wr[f] * av[f];
    wt[(size_t)v * DIM + k] = s;
}

__global__ void k_prep(const float* __restrict__ x, unsigned short* __restrict__ xb,
                       const float* __restrict__ W1, unsigned short* __restrict__ B1,
                       const float* __restrict__ W2, unsigned short* __restrict__ B2,
                       const float* __restrict__ a1, float* __restrict__ wt1,
                       const float* __restrict__ a2, float* __restrict__ wt2,
                       const int* __restrict__ dst, int* __restrict__ counts) {
    int b = blockIdx.x, tid = threadIdx.x;
    if (b < 5000) {
        do_cast(x, xb, b * 256 + tid);
    } else if (b < 5128) {
        do_transW(W1, B1, (b - 5000) * 256 + tid);
    } else if (b < 5256) {
        do_transW(W2, B2, (b - 5128) * 256 + tid);
    } else if (b < 5272) {
        do_wtilde(W1, a1, wt1, (b - 5256) * 256 + tid);
    } else if (b < 5288) {
        do_wtilde(W2, a2, wt2, (b - 5272) * 256 + tid);
    } else {
        int e = (b - 5288) * 256 + tid;
        if (e < N_EDGES) atomicAdd(&counts[dst[e]], 1);
    }
}

// ---------------- CSR build ----------------
__global__ void k_scan(const int* __restrict__ counts, int* __restrict__ offsets,
                       int* __restrict__ cursor) {
    __shared__ int lds[1024];
    int t = threadIdx.x;
    const int CH = (N_NODES + 1023) / 1024;   // 20
    int base = t * CH;
    int sum = 0;
    for (int j = 0; j < CH; j++) {
        int i = base + j;
        if (i < N_NODES) sum += counts[i];
    }
    lds[t] = sum;
    __syncthreads();
    for (int off = 1; off < 1024; off <<= 1) {
        int other = (t >= off) ? lds[t - off] : 0;
        __syncthreads();
        lds[t] += other;
        __syncthreads();
    }
    int excl = lds[t] - sum;
    int run = excl;
    for (int j = 0; j < CH; j++) {
        int i = base + j;
        if (i < N_NODES) {
            offsets[i] = run;
            cursor[i] = run;
            run += counts[i];
        }
    }
    if (t == 0) offsets[N_NODES] = N_EDGES;
}

__global__ void k_fill(const int* __restrict__ src, const int* __restrict__ dst,
                       int* __restrict__ cursor, int* __restrict__ csr_src) {
    int e = blockIdx.x * blockDim.x + threadIdx.x;
    if (e >= N_EDGES) return;
    int d = dst[e];
    int p = atomicAdd(&cursor[d], 1);
    csr_src[p] = src[e];
}

// ---------------- fused GEMM + attention logits (independent roles, shared 16KB LDS) ----------
#define MFMA(a, b, c) __builtin_amdgcn_mfma_f32_16x16x32_bf16(a, b, c, 0, 0, 0)

__global__ __launch_bounds__(256, 8) void k_gemm_als(const unsigned short* __restrict__ A,
                                                     const unsigned short* __restrict__ Bt,
                                                     unsigned short* __restrict__ Hout,
                                                     const float* __restrict__ wt,
                                                     float* __restrict__ als,
                                                     float* __restrict__ ald) {
    __shared__ __align__(16) char sbuf[16384];
    const int tid = threadIdx.x;

    if (blockIdx.x < GEMM_BLOCKS) {
        unsigned short* lds = (unsigned short*)sbuf;
        // bijective XCD swizzle: 2504 = 8 * 313 exactly
        const int orig = blockIdx.x;
        const int wgid = (orig & 7) * 313 + (orig >> 3);
        const int mb = wgid >> 3, nb = wgid & 7;
        const int m0 = mb * BM, n0 = nb * BN;
        const int lane = tid & 63, wid = tid >> 6;
        const int wm = wid >> 1, wn = wid & 1;
        const int lr = lane & 15, kq = lane >> 4;

        f32x4 acc[2][2];
#pragma unroll
        for (int i = 0; i < 2; i++)
#pragma unroll
            for (int j = 0; j < 2; j++) acc[i][j] = (f32x4){0.f, 0.f, 0.f, 0.f};

#pragma unroll 1
        for (int t = 0; t < 8; t++) {
            const int k0 = t * BK;
#pragma unroll
            for (int it = 0; it < 4; it++) {
                const int region = it >> 1;              // 0=A 1=B
                int c = (it & 1) * 256 + tid;            // 0..511
                int row = c >> 3;                        // 0..63
                int sl = (c & 7) ^ (row & 7);            // inverse-swizzled source slot
                int koff = k0 + sl * 8;
                const unsigned short* srcp;
                if (region == 0) {
                    int ar = m0 + row; ar = ar < N_NODES ? ar : N_NODES - 1;
                    srcp = A + (size_t)ar * DIM + koff;
                } else {
                    srcp = Bt + (size_t)(n0 + row) * DIM + koff;
                }
                unsigned short* lb = lds + region * 4096 + ((it & 1) * 256 + (tid & 192)) * 8;
                gl_lds16(srcp, lb);
            }
            asm volatile("s_waitcnt vmcnt(0)" ::: "memory");
            __syncthreads();

#pragma unroll
            for (int ks = 0; ks < 2; ks++) {
                bf16x8 ah[2], bh[2];
#pragma unroll
                for (int tm = 0; tm < 2; tm++) {
                    int row = wm * 32 + tm * 16 + lr;
                    int ph = (ks * 4 + kq) ^ (row & 7);
                    ah[tm] = __builtin_bit_cast(bf16x8,
                        *reinterpret_cast<const short8*>(lds + row * 64 + ph * 8));
                }
#pragma unroll
                for (int tn = 0; tn < 2; tn++) {
                    int col = wn * 32 + tn * 16 + lr;
                    int ph = (ks * 4 + kq) ^ (col & 7);
                    bh[tn] = __builtin_bit_cast(bf16x8,
                        *reinterpret_cast<const short8*>(lds + 4096 + col * 64 + ph * 8));
                }
#pragma unroll
                for (int tm = 0; tm < 2; tm++)
#pragma unroll
                    for (int tn = 0; tn < 2; tn++)
                        acc[tm][tn] = MFMA(ah[tm], bh[tn], acc[tm][tn]);
            }
            if (t < 7) __syncthreads();
        }

#pragma unroll
        for (int tm = 0; tm < 2; tm++)
#pragma unroll
            for (int tn = 0; tn < 2; tn++) {
                int col = n0 + wn * 32 + tn * 16 + lr;
#pragma unroll
                for (int r4 = 0; r4 < 4; r4++) {
                    int row = m0 + wm * 32 + tm * 16 + kq * 4 + r4;
                    if (row < N_NODES) Hout[(size_t)row * DIM + col] = f32_to_bf16(acc[tm][tn][r4]);
                }
            }
    } else {
        // ---- als role ----
        float* wl = (float*)sbuf;   // 8*DIM floats = 16 KB
        for (int i = tid; i < 8 * DIM / 4; i += 256)
            reinterpret_cast<float4*>(wl)[i] = reinterpret_cast<const float4*>(wt)[i];
        __syncthreads();
        int n = (blockIdx.x - GEMM_BLOCKS) * 4 + (tid >> 6);
        if (n >= N_NODES) return;
        int lane = tid & 63;
        short8 xv8 = *reinterpret_cast<const short8*>(A + (size_t)n * DIM + lane * 8);
        float xv[8];
#pragma unroll
        for (int j = 0; j < 8; j++) xv[j] = bf16_to_f32((unsigned short)xv8[j]);
        float p[8] = {0.f, 0.f, 0.f, 0.f, 0.f, 0.f, 0.f, 0.f};
#pragma unroll
        for (int j = 0; j < 8; j++) {
            int k = lane * 8 + j;
#pragma unroll
            for (int v = 0; v < 8; v++) p[v] += xv[j] * wl[v * DIM + k];
        }
#pragma unroll
        for (int off = 1; off < 64; off <<= 1)
#pragma unroll
            for (int v = 0; v < 8; v++) p[v] += __shfl_xor(p[v], off);
        if (lane == 0) {
            float4 s = {p[0], p[2], p[4], p[6]};
            float4 d = {p[1], p[3], p[5], p[7]};
            *reinterpret_cast<float4*>(als + (size_t)n * 4) = s;
            *reinterpret_cast<float4*>(ald + (size_t)n * 4) = d;
        }
    }
}

// ---------------- single-pass aggregation: ONE wave per node, uint4 loads, 4-deep unroll ------
// (best measured variant: R10 — VGPR 32, ~54 us/dispatch)
// lane covers 8 cols at c0 = lane*8; head hd = lane>>4. alpha = exp(leaky(e))/sum.
#define EDGE_STEP(ee, hq)                                                   \
    {                                                                       \
        float sc_ = (ee) + aldh;                                            \
        sc_ = fmaxf(sc_, NEG_SLOPE * sc_);                                  \
        float w_ = __expf(sc_);                                             \
        s += w_;                                                            \
        acc[0] += w_ * bits_f32((hq).x << 16);                              \
        acc[1] += w_ * bits_f32((hq).x & 0xFFFF0000u);                      \
        acc[2] += w_ * bits_f32((hq).y << 16);                              \
        acc[3] += w_ * bits_f32((hq).y & 0xFFFF0000u);                      \
        acc[4] += w_ * bits_f32((hq).z << 16);                              \
        acc[5] += w_ * bits_f32((hq).z & 0xFFFF0000u);                      \
        acc[6] += w_ * bits_f32((hq).w << 16);                              \
        acc[7] += w_ * bits_f32((hq).w & 0xFFFF0000u);                      \
    }

__global__ __launch_bounds__(256) void k_agg(const int* __restrict__ offsets,
                                             const int* __restrict__ csr_src,
                                             const float* __restrict__ als,
                                             const float* __restrict__ ald,
                                             const unsigned short* __restrict__ H,
                                             const float* __restrict__ bias,
                                             const float* __restrict__ resid_f32,
                                             const unsigned short* __restrict__ resid_b16,
                                             float* __restrict__ out_f32,
                                             unsigned short* __restrict__ out_b16) {
    int v = (blockIdx.x * blockDim.x + threadIdx.x) >> 6;
    if (v >= N_NODES) return;
    int lane = threadIdx.x & 63;
    int c0 = lane * 8;
    int hd = lane >> 4;

    int beg = offsets[v], deg = offsets[v + 1] - beg;
    float aldh = ald[v * 4 + hd];
    const int* cp = csr_src + beg;

    float acc[8] = {0.f, 0.f, 0.f, 0.f, 0.f, 0.f, 0.f, 0.f};
    float s = 0.f;
    int i = 0;
    for (; i + 4 <= deg; i += 4) {
        int u0 = cp[i], u1 = cp[i + 1], u2 = cp[i + 2], u3 = cp[i + 3];
        float e0 = als[u0 * 4 + hd];
        float e1 = als[u1 * 4 + hd];
        float e2 = als[u2 * 4 + hd];
        float e3 = als[u3 * 4 + hd];
        uint4 h0 = *reinterpret_cast<const uint4*>(H + (size_t)u0 * DIM + c0);
        uint4 h1 = *reinterpret_cast<const uint4*>(H + (size_t)u1 * DIM + c0);
        uint4 h2 = *reinterpret_cast<const uint4*>(H + (size_t)u2 * DIM + c0);
        uint4 h3 = *reinterpret_cast<const uint4*>(H + (size_t)u3 * DIM + c0);
        EDGE_STEP(e0, h0);
        EDGE_STEP(e1, h1);
        EDGE_STEP(e2, h2);
        EDGE_STEP(e3, h3);
    }
    for (; i < deg; i++) {
        int u0 = cp[i];
        float e0 = als[u0 * 4 + hd];
        uint4 h0 = *reinterpret_cast<const uint4*>(H + (size_t)u0 * DIM + c0);
        EDGE_STEP(e0, h0);
    }

    float inv = deg > 0 ? 1.0f / s : 0.f;
    const float4* bp = reinterpret_cast<const float4*>(bias + c0);
    float4 b0 = bp[0], b1 = bp[1];
    float bv[8] = {b0.x, b0.y, b0.z, b0.w, b1.x, b1.y, b1.z, b1.w};
    float o[8];
#pragma unroll
    for (int j = 0; j < 8; j++) {
        float t = acc[j] * inv + bv[j];
        o[j] = t > 0.f ? t : expm1f(t);
    }
    if (resid_f32) {
        const float4* rp = reinterpret_cast<const float4*>(resid_f32 + (size_t)v * DIM + c0);
        float4 r0 = rp[0], r1 = rp[1];
        o[0] += r0.x; o[1] += r0.y; o[2] += r0.z; o[3] += r0.w;
        o[4] += r1.x; o[5] += r1.y; o[6] += r1.z; o[7] += r1.w;
    } else {
        short8 rv = *reinterpret_cast<const short8*>(resid_b16 + (size_t)v * DIM + c0);
#pragma unroll
        for (int j = 0; j < 8; j++) o[j] += bf16_to_f32((unsigned short)rv[j]);
    }
    if (out_f32) {
        float4 w0 = {o[0], o[1], o[2], o[3]};
        float4 w1 = {o[4], o[5], o[6], o[7]};
        float4* op = reinterpret_cast<float4*>(out_f32 + (size_t)v * DIM + c0);
        op[0] = w0;
        op[1] = w1;
    }
    if (out_b16) {
        short8 ob;
#pragma unroll
        for (int j = 0; j < 8; j++) ob[j] = (short)f32_to_bf16(o[j]);
        *reinterpret_cast<short8*>(out_b16 + (size_t)v * DIM + c0) = ob;
    }
}

extern "C" void kernel_launch(void* const* d_in, const int* in_sizes, int n_in,
                              void* d_out, int out_size, void* d_ws, size_t ws_size,
                              hipStream_t stream) {
    const float* x = (const float*)d_in[0];
    const int* ei = (const int*)d_in[1];
    const int* src = ei;
    const int* dst = ei + N_EDGES;
    const float* W1 = (const float*)d_in[5];
    const float* a1 = (const float*)d_in[6];
    const float* b1 = (const float*)d_in[7];
    const float* W2 = (const float*)d_in[8];
    const float* a2 = (const float*)d_in[9];
    const float* b2 = (const float*)d_in[10];

    char* ws = (char*)d_ws;
    size_t off = 0;
    auto alloc = [&](size_t bytes) -> void* {
        void* p = ws + off;
        off += (bytes + 255) & ~(size_t)255;
        return p;
    };
    unsigned short* xb   = (unsigned short*)alloc((size_t)N_NODES * DIM * 2);  // x bf16, then x1 bf16
    unsigned short* h    = (unsigned short*)alloc((size_t)N_NODES * DIM * 2);
    float* als           = (float*)alloc((size_t)N_NODES * 8 * 4);  // als | ald contiguous
    float* ald           = als + (size_t)N_NODES * 4;
    unsigned short* B1   = (unsigned short*)alloc((size_t)DIM * DIM * 2);
    unsigned short* B2   = (unsigned short*)alloc((size_t)DIM * DIM * 2);
    float* wt1           = (float*)alloc((size_t)8 * DIM * 4);
    float* wt2           = (float*)alloc((size_t)8 * DIM * 4);
    int* offsets         = (int*)alloc((size_t)(N_NODES + 1) * 4);
    int* cursor          = (int*)alloc((size_t)N_NODES * 4);
    int* counts          = (int*)alloc((size_t)N_NODES * 4);
    int* csr_src         = (int*)alloc((size_t)N_EDGES * 4);

    const int EB = (N_EDGES + 255) / 256;   // 1250

    // prologue: zero counts, then fused cast/transW/wtilde/hist, scan, fill
    hipMemsetAsync(counts, 0, (size_t)N_NODES * 4, stream);
    k_prep<<<5288 + EB, 256, 0, stream>>>(x, xb, W1, B1, W2, B2, a1, wt1, a2, wt2, dst, counts);
    k_scan<<<1, 1024, 0, stream>>>(counts, offsets, cursor);
    k_fill<<<EB, 256, 0, stream>>>(src, dst, cursor, csr_src);

    const int FUSED_BLOCKS = GEMM_BLOCKS + ALS_BLOCKS;   // 7504
    const int AGG_BLOCKS = (N_NODES + 3) / 4;            // 5000 (1 wave/node)

    // ---- layer 1 ----
    k_gemm_als<<<FUSED_BLOCKS, 256, 0, stream>>>(xb, B1, h, wt1, als, ald);
    // resid = x (f32); output bf16 x1 into xb (k_agg doesn't read xb)
    k_agg<<<AGG_BLOCKS, 256, 0, stream>>>(offsets, csr_src, als, ald, h, b1,
                                          x, nullptr, nullptr, xb);

    // ---- layer 2 ----
    k_gemm_als<<<FUSED_BLOCKS, 256, 0, stream>>>(xb, B2, h, wt2, als, ald);
    // resid = x1 (bf16); output f32 d_out
    k_agg<<<AGG_BLOCKS, 256, 0, stream>>>(offsets, csr_src, als, ald, h, b2,
                                          nullptr, xb, (float*)d_out, nullptr);
}